// Round 1
// baseline (89.403 us; speedup 1.0000x reference)
//
#include <hip/hip_runtime.h>

// Problem constants (from setup_inputs): B=32, N=2048, D=512, O=2
#define BB 32
#define NN 2048
#define DD 512
#define CC 16            // number of chunks along N
#define LL (NN / CC)     // 128 steps per chunk

// State recurrence (verified against reference algebra):
//   m0' = a0*m0 + g
//   m1' = a1*m1 + m0'            = a0*m0 + a1*m1 + g
//   w'  = e*w + c0*g + c1*m0' + c2*m1'
// Matrix M (lower triangular, gate-only):
//   [a0      0      0 ]
//   [a0      a1     0 ]
//   [(c1+c2)a0  c2*a1  e]   with input coeff (1, 1, c0+c1+c2)*g

// ---------------- Pass 1: per-chunk local scan (zero init) + chunk matrix ----------------
__global__ __launch_bounds__(256) void pass1_local(
    const float* __restrict__ grad,   // (B,N,D)
    const float* __restrict__ am,     // (2,B,N)
    const float* __restrict__ cm,     // (3,B,N)
    const float* __restrict__ dec,    // (B,N)
    float* __restrict__ Mtot,         // (B,C,6)
    float* __restrict__ local_end)    // (B,C,3,D)
{
    const int c = blockIdx.x;
    const int b = blockIdx.y;
    const int d2 = threadIdx.x;       // float2 lane index; d = 2*d2
    const float2* g2 = (const float2*)grad;

    const float* a0p = am + (size_t)(0 * BB + b) * NN;
    const float* a1p = am + (size_t)(1 * BB + b) * NN;
    const float* c0p = cm + (size_t)(0 * BB + b) * NN;
    const float* c1p = cm + (size_t)(1 * BB + b) * NN;
    const float* c2p = cm + (size_t)(2 * BB + b) * NN;
    const float* dp  = dec + (size_t)b * NN;

    float2 m0 = {0.f, 0.f}, m1 = {0.f, 0.f}, w = {0.f, 0.f};
    float p00 = 1.f, p10 = 0.f, p11 = 1.f, p20 = 0.f, p21 = 0.f, p22 = 1.f;

    const int t0 = c * LL;
    #pragma unroll 4
    for (int t = t0; t < t0 + LL; ++t) {
        const float a0 = a0p[t], a1 = a1p[t];
        const float c0 = c0p[t], c1 = c1p[t], c2 = c2p[t];
        const float e  = 1.0f - dp[t];
        const float2 g = g2[(((size_t)(b * NN + t)) * DD >> 1) + d2];

        // state update (exact reference recurrence)
        m0.x = fmaf(a0, m0.x, g.x);  m0.y = fmaf(a0, m0.y, g.y);
        m1.x = fmaf(a1, m1.x, m0.x); m1.y = fmaf(a1, m1.y, m0.y);
        w.x = fmaf(e, w.x, fmaf(c0, g.x, fmaf(c1, m0.x, c2 * m1.x)));
        w.y = fmaf(e, w.y, fmaf(c0, g.y, fmaf(c1, m0.y, c2 * m1.y)));

        // matrix accumulation: P <- M_t * P  (lower triangular)
        const float k0 = (c1 + c2) * a0;
        const float k1 = c2 * a1;
        const float n00 = a0 * p00;
        const float n10 = fmaf(a0, p00, a1 * p10);
        const float n11 = a1 * p11;
        const float n20 = fmaf(k0, p00, fmaf(k1, p10, e * p20));
        const float n21 = fmaf(k1, p11, e * p21);
        const float n22 = e * p22;
        p00 = n00; p10 = n10; p11 = n11; p20 = n20; p21 = n21; p22 = n22;
    }

    float2* le = (float2*)local_end;
    const size_t base = ((size_t)(b * CC + c) * 3) * DD >> 1;  // in float2 units
    le[base + d2]                = m0;
    le[base + (DD >> 1) + d2]    = m1;
    le[base + 2 * (DD >> 1) + d2] = w;

    if (threadIdx.x == 0) {
        float* mt = Mtot + (size_t)(b * CC + c) * 6;
        mt[0] = p00; mt[1] = p10; mt[2] = p11;
        mt[3] = p20; mt[4] = p21; mt[5] = p22;
    }
}

// ---------------- Pass 2: carry scan across chunks; also writes W_t row + next_last ----------------
__global__ __launch_bounds__(256) void pass2_carry(
    const float* __restrict__ Wt,        // (B,D)
    const float* __restrict__ lm,        // (2,B,D)
    const float* __restrict__ Mtot,      // (B,C,6)
    const float* __restrict__ local_end, // (B,C,3,D)
    float* __restrict__ carry,           // (B,C,3,D)
    float* __restrict__ out)             // update (B,N+1,D) then next_last (2,B,D)
{
    const int b = blockIdx.x;
    const int d2 = threadIdx.x;

    const float2* lm2 = (const float2*)lm;
    const float2* wt2 = (const float2*)Wt;
    float2 s0 = lm2[(((size_t)(0 * BB + b)) * DD >> 1) + d2];
    float2 s1 = lm2[(((size_t)(1 * BB + b)) * DD >> 1) + d2];
    float2 s2 = wt2[(((size_t)b) * DD >> 1) + d2];

    float2* out2 = (float2*)out;
    // update[b][0][:] = W_t
    out2[(((size_t)b * (NN + 1)) * DD >> 1) + d2] = s2;

    float2* cy = (float2*)carry;
    const float2* le = (const float2*)local_end;

    for (int c = 0; c < CC; ++c) {
        const size_t base = ((size_t)(b * CC + c) * 3) * DD >> 1;
        cy[base + d2]                 = s0;
        cy[base + (DD >> 1) + d2]     = s1;
        cy[base + 2 * (DD >> 1) + d2] = s2;

        const float* mt = Mtot + (size_t)(b * CC + c) * 6;
        const float p00 = mt[0], p10 = mt[1], p11 = mt[2];
        const float p20 = mt[3], p21 = mt[4], p22 = mt[5];

        const float2 l0 = le[base + d2];
        const float2 l1 = le[base + (DD >> 1) + d2];
        const float2 l2 = le[base + 2 * (DD >> 1) + d2];

        float2 n0, n1, n2;
        n0.x = fmaf(p00, s0.x, l0.x);
        n0.y = fmaf(p00, s0.y, l0.y);
        n1.x = fmaf(p10, s0.x, fmaf(p11, s1.x, l1.x));
        n1.y = fmaf(p10, s0.y, fmaf(p11, s1.y, l1.y));
        n2.x = fmaf(p20, s0.x, fmaf(p21, s1.x, fmaf(p22, s2.x, l2.x)));
        n2.y = fmaf(p20, s0.y, fmaf(p21, s1.y, fmaf(p22, s2.y, l2.y)));
        s0 = n0; s1 = n1; s2 = n2;
    }

    // next_last_momentum (2,B,D) follows update in d_out
    const size_t nlbase = ((size_t)BB * (NN + 1) * DD) >> 1;  // float2 units
    out2[nlbase + (((size_t)(0 * BB + b)) * DD >> 1) + d2] = s0;
    out2[nlbase + (((size_t)(1 * BB + b)) * DD >> 1) + d2] = s1;
}

// ---------------- Pass 3: re-run exact recurrence per chunk from carry, write update[:,1:,:] ----------------
__global__ __launch_bounds__(256) void pass3_final(
    const float* __restrict__ grad,
    const float* __restrict__ am,
    const float* __restrict__ cm,
    const float* __restrict__ dec,
    const float* __restrict__ carry,
    float* __restrict__ out)
{
    const int c = blockIdx.x;
    const int b = blockIdx.y;
    const int d2 = threadIdx.x;

    const float2* cy = (const float2*)carry;
    const size_t base = ((size_t)(b * CC + c) * 3) * DD >> 1;
    float2 m0 = cy[base + d2];
    float2 m1 = cy[base + (DD >> 1) + d2];
    float2 w  = cy[base + 2 * (DD >> 1) + d2];

    const float* a0p = am + (size_t)(0 * BB + b) * NN;
    const float* a1p = am + (size_t)(1 * BB + b) * NN;
    const float* c0p = cm + (size_t)(0 * BB + b) * NN;
    const float* c1p = cm + (size_t)(1 * BB + b) * NN;
    const float* c2p = cm + (size_t)(2 * BB + b) * NN;
    const float* dp  = dec + (size_t)b * NN;

    const float2* g2 = (const float2*)grad;
    float2* out2 = (float2*)out;

    const int t0 = c * LL;
    #pragma unroll 4
    for (int t = t0; t < t0 + LL; ++t) {
        const float a0 = a0p[t], a1 = a1p[t];
        const float c0 = c0p[t], c1 = c1p[t], c2 = c2p[t];
        const float e  = 1.0f - dp[t];
        const float2 g = g2[(((size_t)(b * NN + t)) * DD >> 1) + d2];

        m0.x = fmaf(a0, m0.x, g.x);  m0.y = fmaf(a0, m0.y, g.y);
        m1.x = fmaf(a1, m1.x, m0.x); m1.y = fmaf(a1, m1.y, m0.y);
        w.x = fmaf(e, w.x, fmaf(c0, g.x, fmaf(c1, m0.x, c2 * m1.x)));
        w.y = fmaf(e, w.y, fmaf(c0, g.y, fmaf(c1, m0.y, c2 * m1.y)));

        // update[b][t+1][:]
        out2[(((size_t)(b * (NN + 1) + (t + 1))) * DD >> 1) + d2] = w;
    }
}

extern "C" void kernel_launch(void* const* d_in, const int* in_sizes, int n_in,
                              void* d_out, int out_size, void* d_ws, size_t ws_size,
                              hipStream_t stream) {
    const float* Wt   = (const float*)d_in[0];   // (B,D)
    // d_in[1] = x_t, unused by reference
    const float* grad = (const float*)d_in[2];   // (B,N,D)
    const float* lm   = (const float*)d_in[3];   // (2,B,D)
    const float* am   = (const float*)d_in[4];   // (2,B,N,1)
    const float* cm   = (const float*)d_in[5];   // (3,B,N)
    const float* dec  = (const float*)d_in[6];   // (B,N,1)
    float* out = (float*)d_out;

    // workspace layout
    // Mtot: B*C*6 floats; local_end: B*C*3*D; carry: B*C*3*D
    char* ws = (char*)d_ws;
    float* Mtot      = (float*)(ws);
    float* local_end = (float*)(ws + (size_t)BB * CC * 6 * sizeof(float));          // 12 KiB offset
    float* carry     = (float*)(ws + (size_t)BB * CC * 6 * sizeof(float)
                                   + (size_t)BB * CC * 3 * DD * sizeof(float));     // +3 MiB

    dim3 gridA(CC, BB);
    pass1_local<<<gridA, 256, 0, stream>>>(grad, am, cm, dec, Mtot, local_end);
    pass2_carry<<<BB, 256, 0, stream>>>(Wt, lm, Mtot, local_end, carry, out);
    pass3_final<<<gridA, 256, 0, stream>>>(grad, am, cm, dec, carry, out);
}

// Round 3
// 83.542 us; speedup vs baseline: 1.0702x; 1.0702x over previous
//
#include <hip/hip_runtime.h>

// Problem constants (from setup_inputs): B=32, N=2048, D=512, O=2
#define BB 32
#define NN 2048
#define DD 512
#define CC 32            // number of chunks along N
#define LL (NN / CC)     // 64 steps per chunk

// clang native vector — accepted by __builtin_nontemporal_load/store
typedef float vf2 __attribute__((ext_vector_type(2)));

// State recurrence (verified against reference algebra):
//   m0' = a0*m0 + g
//   m1' = a1*m1 + m0'
//   w'  = e*w + c0*g + c1*m0' + c2*m1'
// Chunk transition matrix P (lower triangular, gate-only, 6 scalars).

// ---------------- Pass 1: per-chunk local scan (zero init) + chunk matrix ----------------
__global__ __launch_bounds__(256) void pass1_local(
    const float* __restrict__ grad,   // (B,N,D)
    const float* __restrict__ am,     // (2,B,N)
    const float* __restrict__ cm,     // (3,B,N)
    const float* __restrict__ dec,    // (B,N)
    float* __restrict__ Mtot,         // (B,C,6)
    float* __restrict__ local_end)    // (B,C,3,D)
{
    const int c = blockIdx.x;
    const int b = blockIdx.y;
    const int d2 = threadIdx.x;       // vf2 lane index; d = 2*d2
    const vf2* g2 = (const vf2*)grad;

    const float* a0p = am + (size_t)(0 * BB + b) * NN;
    const float* a1p = am + (size_t)(1 * BB + b) * NN;
    const float* c0p = cm + (size_t)(0 * BB + b) * NN;
    const float* c1p = cm + (size_t)(1 * BB + b) * NN;
    const float* c2p = cm + (size_t)(2 * BB + b) * NN;
    const float* dp  = dec + (size_t)b * NN;

    vf2 m0 = {0.f, 0.f}, m1 = {0.f, 0.f}, w = {0.f, 0.f};
    float p00 = 1.f, p10 = 0.f, p11 = 1.f, p20 = 0.f, p21 = 0.f, p22 = 1.f;

    const int t0 = c * LL;
    #pragma unroll 8
    for (int t = t0; t < t0 + LL; ++t) {
        const float a0 = a0p[t], a1 = a1p[t];
        const float c0 = c0p[t], c1 = c1p[t], c2 = c2p[t];
        const float e  = 1.0f - dp[t];
        const vf2 g = g2[(((size_t)(b * NN + t)) * DD >> 1) + d2];

        // state update (exact reference recurrence)
        m0.x = fmaf(a0, m0.x, g.x);  m0.y = fmaf(a0, m0.y, g.y);
        m1.x = fmaf(a1, m1.x, m0.x); m1.y = fmaf(a1, m1.y, m0.y);
        w.x = fmaf(e, w.x, fmaf(c0, g.x, fmaf(c1, m0.x, c2 * m1.x)));
        w.y = fmaf(e, w.y, fmaf(c0, g.y, fmaf(c1, m0.y, c2 * m1.y)));

        // matrix accumulation: P <- M_t * P  (lower triangular)
        const float k0 = (c1 + c2) * a0;
        const float k1 = c2 * a1;
        const float n00 = a0 * p00;
        const float n10 = fmaf(a0, p00, a1 * p10);
        const float n11 = a1 * p11;
        const float n20 = fmaf(k0, p00, fmaf(k1, p10, e * p20));
        const float n21 = fmaf(k1, p11, e * p21);
        const float n22 = e * p22;
        p00 = n00; p10 = n10; p11 = n11; p20 = n20; p21 = n21; p22 = n22;
    }

    vf2* le = (vf2*)local_end;
    const size_t base = ((size_t)(b * CC + c) * 3) * DD >> 1;  // in vf2 units
    le[base + d2]                 = m0;
    le[base + (DD >> 1) + d2]     = m1;
    le[base + 2 * (DD >> 1) + d2] = w;

    if (threadIdx.x == 0) {
        float* mt = Mtot + (size_t)(b * CC + c) * 6;
        mt[0] = p00; mt[1] = p10; mt[2] = p11;
        mt[3] = p20; mt[4] = p21; mt[5] = p22;
    }
}

// ---------------- Pass 2 (fused): each block computes its own carry, then final scan ----------------
__global__ __launch_bounds__(256) void pass3_fused(
    const float* __restrict__ grad,
    const float* __restrict__ am,
    const float* __restrict__ cm,
    const float* __restrict__ dec,
    const float* __restrict__ Wt,        // (B,D)
    const float* __restrict__ lm,        // (2,B,D)
    const float* __restrict__ Mtot,      // (B,C,6)
    const float* __restrict__ local_end, // (B,C,3,D)
    float* __restrict__ out)             // update (B,N+1,D) then next_last (2,B,D)
{
    const int c = blockIdx.x;
    const int b = blockIdx.y;
    const int d2 = threadIdx.x;

    // ---- initial global state ----
    const vf2* lm2 = (const vf2*)lm;
    const vf2* wt2 = (const vf2*)Wt;
    vf2 s0 = lm2[(((size_t)(0 * BB + b)) * DD >> 1) + d2];
    vf2 s1 = lm2[(((size_t)(1 * BB + b)) * DD >> 1) + d2];
    vf2 s2 = wt2[(((size_t)b) * DD >> 1) + d2];

    // ---- redundant carry prefix: apply chunks 0..c-1 ----
    const vf2* le = (const vf2*)local_end;
    for (int cc = 0; cc < c; ++cc) {
        const float* mt = Mtot + (size_t)(b * CC + cc) * 6;
        const float p00 = mt[0], p10 = mt[1], p11 = mt[2];
        const float p20 = mt[3], p21 = mt[4], p22 = mt[5];

        const size_t base = ((size_t)(b * CC + cc) * 3) * DD >> 1;
        const vf2 l0 = le[base + d2];
        const vf2 l1 = le[base + (DD >> 1) + d2];
        const vf2 l2 = le[base + 2 * (DD >> 1) + d2];

        vf2 n0, n1, n2;
        n0.x = fmaf(p00, s0.x, l0.x);
        n0.y = fmaf(p00, s0.y, l0.y);
        n1.x = fmaf(p10, s0.x, fmaf(p11, s1.x, l1.x));
        n1.y = fmaf(p10, s0.y, fmaf(p11, s1.y, l1.y));
        n2.x = fmaf(p20, s0.x, fmaf(p21, s1.x, fmaf(p22, s2.x, l2.x)));
        n2.y = fmaf(p20, s0.y, fmaf(p21, s1.y, fmaf(p22, s2.y, l2.y)));
        s0 = n0; s1 = n1; s2 = n2;
    }

    vf2* out2 = (vf2*)out;
    if (c == 0) {
        // update[b][0][:] = W_t  (s2 == W_t here)
        __builtin_nontemporal_store(s2, &out2[(((size_t)b * (NN + 1)) * DD >> 1) + d2]);
    }

    // ---- final scan over this chunk, writing update[b][t+1][:] ----
    const float* a0p = am + (size_t)(0 * BB + b) * NN;
    const float* a1p = am + (size_t)(1 * BB + b) * NN;
    const float* c0p = cm + (size_t)(0 * BB + b) * NN;
    const float* c1p = cm + (size_t)(1 * BB + b) * NN;
    const float* c2p = cm + (size_t)(2 * BB + b) * NN;
    const float* dp  = dec + (size_t)b * NN;

    const vf2* g2 = (const vf2*)grad;
    vf2 m0 = s0, m1 = s1, w = s2;

    const int t0 = c * LL;
    #pragma unroll 8
    for (int t = t0; t < t0 + LL; ++t) {
        const float a0 = a0p[t], a1 = a1p[t];
        const float c0 = c0p[t], c1 = c1p[t], c2 = c2p[t];
        const float e  = 1.0f - dp[t];
        const vf2 g = __builtin_nontemporal_load(
            &g2[(((size_t)(b * NN + t)) * DD >> 1) + d2]);

        m0.x = fmaf(a0, m0.x, g.x);  m0.y = fmaf(a0, m0.y, g.y);
        m1.x = fmaf(a1, m1.x, m0.x); m1.y = fmaf(a1, m1.y, m0.y);
        w.x = fmaf(e, w.x, fmaf(c0, g.x, fmaf(c1, m0.x, c2 * m1.x)));
        w.y = fmaf(e, w.y, fmaf(c0, g.y, fmaf(c1, m0.y, c2 * m1.y)));

        __builtin_nontemporal_store(
            w, &out2[(((size_t)(b * (NN + 1) + (t + 1))) * DD >> 1) + d2]);
    }

    if (c == CC - 1) {
        // next_last_momentum (2,B,D) follows update in d_out
        const size_t nlbase = ((size_t)BB * (NN + 1) * DD) >> 1;  // vf2 units
        __builtin_nontemporal_store(
            m0, &out2[nlbase + (((size_t)(0 * BB + b)) * DD >> 1) + d2]);
        __builtin_nontemporal_store(
            m1, &out2[nlbase + (((size_t)(1 * BB + b)) * DD >> 1) + d2]);
    }
}

extern "C" void kernel_launch(void* const* d_in, const int* in_sizes, int n_in,
                              void* d_out, int out_size, void* d_ws, size_t ws_size,
                              hipStream_t stream) {
    const float* Wt   = (const float*)d_in[0];   // (B,D)
    // d_in[1] = x_t, unused by reference
    const float* grad = (const float*)d_in[2];   // (B,N,D)
    const float* lm   = (const float*)d_in[3];   // (2,B,D)
    const float* am   = (const float*)d_in[4];   // (2,B,N,1)
    const float* cm   = (const float*)d_in[5];   // (3,B,N)
    const float* dec  = (const float*)d_in[6];   // (B,N,1)
    float* out = (float*)d_out;

    // workspace layout: Mtot (B*C*6 floats), local_end (B*C*3*D floats)
    char* ws = (char*)d_ws;
    float* Mtot      = (float*)(ws);
    float* local_end = (float*)(ws + (size_t)BB * CC * 6 * sizeof(float));

    dim3 gridA(CC, BB);
    pass1_local<<<gridA, 256, 0, stream>>>(grad, am, cm, dec, Mtot, local_end);
    pass3_fused<<<gridA, 256, 0, stream>>>(grad, am, cm, dec, Wt, lm, Mtot,
                                           local_end, out);
}